// Round 18
// baseline (161.347 us; speedup 1.0000x reference)
//
#include <hip/hip_runtime.h>
#include <hip/hip_bf16.h>
#include <hip/hip_fp8.h>

#define N_NODES 40000
#define N_EDGES 640000
#define ETOT    (N_NODES + N_EDGES)   // 680000
#define D_DIM   128
#define HC      256                   // H*C
#define NEG     0.2f
#define CAP     64                    // fixed CSR row stride (max deg well under 64)

typedef short short8v __attribute__((ext_vector_type(8)));
typedef float f32x4 __attribute__((ext_vector_type(4)));
typedef float f32x2 __attribute__((ext_vector_type(2)));

static __device__ __forceinline__ float bf2f(unsigned short u) {
    return __uint_as_float(((unsigned)u) << 16);
}
static __device__ __forceinline__ unsigned short f2bf(float f) {
    __hip_bfloat16 b = __float2bfloat16(f);
    unsigned short r;
    __builtin_memcpy(&r, &b, 2);
    return r;
}
static __device__ __forceinline__ unsigned char f2fp8(float f) {
    __hip_fp8_e4m3 v(f);
    return (unsigned char)v.__x;
}
static __device__ __forceinline__ unsigned int pk4fp8(float a, float b, float c, float d) {
#if __has_builtin(__builtin_amdgcn_cvt_pk_fp8_f32)
    int w = __builtin_amdgcn_cvt_pk_fp8_f32(a, b, 0, false);
    w = __builtin_amdgcn_cvt_pk_fp8_f32(c, d, w, true);
    return (unsigned int)w;
#else
    return (unsigned int)f2fp8(a) | ((unsigned int)f2fp8(b) << 8) |
           ((unsigned int)f2fp8(c) << 16) | ((unsigned int)f2fp8(d) << 24);
#endif
}
static __device__ __forceinline__ void cvt4fp8(unsigned int w, float* f) {
#if __has_builtin(__builtin_amdgcn_cvt_pk_f32_fp8)
    f32x2 lo = __builtin_amdgcn_cvt_pk_f32_fp8(w, false);
    f32x2 hi = __builtin_amdgcn_cvt_pk_f32_fp8(w, true);
    f[0] = lo[0]; f[1] = lo[1]; f[2] = hi[0]; f[3] = hi[1];
#else
    for (int i = 0; i < 4; i++) {
        __hip_fp8_e4m3 v; v.__x = (unsigned char)(w >> (8 * i));
        f[i] = (float)v;
    }
#endif
}

// ---------------- fused D1: scatter || gemm0(+esd0, 32KB LDS 2-half) || W1cvt || copy ----------
#define SCT_BLKS 665           // 665*1024 >= 680000, 4 edges/thread
#define G0_BLKS  625
#define WCV_BLKS 32            // 8192 float4 of layer-1 W
#define CPY_BLKS 2500          // 1280000 float4, 2 per thread
__global__ __launch_bounds__(256) void fused0_k(const int* __restrict__ ei, int* __restrict__ deg,
                                                unsigned short* __restrict__ csrc,
                                                const float* __restrict__ x,
                                                const float* __restrict__ W,
                                                unsigned char* __restrict__ h8,
                                                const float* __restrict__ a_s,
                                                const float* __restrict__ a_d,
                                                float4* __restrict__ esd,
                                                unsigned short* __restrict__ wbf,
                                                float4* __restrict__ out,
                                                ushort4* __restrict__ xb) {
    __shared__ unsigned short wsd[128 * D_DIM];   // 32 KB (half of W at a time)
    const int b = blockIdx.x;
    const int t = threadIdx.x;
    if (b < SCT_BLKS) {
        const int e0 = b * 1024 + t;
#pragma unroll
        for (int u = 0; u < 4; u++) {
            const int e = e0 + u * 256;
            if (e < ETOT) {
                int ss, dd;
                if (e < N_EDGES) { ss = ei[e]; dd = ei[N_EDGES + e]; }
                else             { ss = e - N_EDGES; dd = ss; }
                int pos = atomicAdd(&deg[dd], 1);
                if (pos < CAP) csrc[dd * CAP + pos] = (unsigned short)ss;
            }
        }
    } else if (b < SCT_BLKS + G0_BLKS) {
        const int blk = b - SCT_BLKS;
        const int wv = t >> 6;
        const int lane = t & 63;
        const int bm = blk * 64 + wv * 16;
        const int l16 = lane & 15;
        const int kg = lane >> 4;      // 0..3
        f32x4 acc[16] = {};
#pragma unroll
        for (int half = 0; half < 2; half++) {
            // stage W rows half*128 .. half*128+127 (fp32 -> bf16, XOR swizzle)
#pragma unroll
            for (int i = 0; i < 8; i++) {
                const int idx = i * 256 + t;          // 0..2047
                const int r = idx >> 4, c = idx & 15; // local row, 16B chunk
                const float* wp = W + ((size_t)(half * 128 + r) * 128) + c * 8;
                float4 w0 = *(const float4*)wp;
                float4 w1 = *(const float4*)(wp + 4);
                short8v v;
                v[0] = (short)f2bf(w0.x); v[1] = (short)f2bf(w0.y);
                v[2] = (short)f2bf(w0.z); v[3] = (short)f2bf(w0.w);
                v[4] = (short)f2bf(w1.x); v[5] = (short)f2bf(w1.y);
                v[6] = (short)f2bf(w1.z); v[7] = (short)f2bf(w1.w);
                *(short8v*)(wsd + r * 128 + ((c ^ (r & 15)) * 8)) = v;
            }
            __syncthreads();
#pragma unroll
            for (int kk = 0; kk < 4; kk++) {
                const int k0 = kk * 32 + kg * 8;
                const float* ap = x + (size_t)(bm + l16) * 128 + k0;
                float4 a0 = *(const float4*)ap;
                float4 a1 = *(const float4*)(ap + 4);
                short8v af;
                af[0] = (short)f2bf(a0.x); af[1] = (short)f2bf(a0.y);
                af[2] = (short)f2bf(a0.z); af[3] = (short)f2bf(a0.w);
                af[4] = (short)f2bf(a1.x); af[5] = (short)f2bf(a1.y);
                af[6] = (short)f2bf(a1.z); af[7] = (short)f2bf(a1.w);
                const int cc = kk * 4 + kg;
#pragma unroll
                for (int n = 0; n < 8; n++) {
                    const int r = n * 16 + l16;       // local row 0..127
                    short8v bf_ = *(const short8v*)(wsd + r * 128 + (((cc ^ l16) & 15) * 8));
                    acc[half * 8 + n] = __builtin_amdgcn_mfma_f32_16x16x32_bf16(af, bf_, acc[half * 8 + n], 0, 0, 0);
                }
            }
            __syncthreads();
        }
        float asv[16], adv[16];
#pragma unroll
        for (int n = 0; n < 16; n++) {
            asv[n] = a_s[n * 16 + l16];
            adv[n] = a_d[n * 16 + l16];
        }
#pragma unroll
        for (int r = 0; r < 4; r++) {
            const int orow = bm + kg * 4 + r;
            float es0 = 0.f, es1 = 0.f, ed0 = 0.f, ed1 = 0.f;
            unsigned int pk[4];
#pragma unroll
            for (int nq = 0; nq < 4; nq++)
                pk[nq] = pk4fp8(acc[nq * 4][r], acc[nq * 4 + 1][r],
                                acc[nq * 4 + 2][r], acc[nq * 4 + 3][r]);
#pragma unroll
            for (int n = 0; n < 8; n++)  { es0 += acc[n][r] * asv[n]; ed0 += acc[n][r] * adv[n]; }
#pragma unroll
            for (int n = 8; n < 16; n++) { es1 += acc[n][r] * asv[n]; ed1 += acc[n][r] * adv[n]; }
            *(uint4*)(h8 + (size_t)orow * 256 + l16 * 16) = make_uint4(pk[0], pk[1], pk[2], pk[3]);
#pragma unroll
            for (int m = 1; m < 16; m <<= 1) {
                es0 += __shfl_xor(es0, m, 16);
                es1 += __shfl_xor(es1, m, 16);
                ed0 += __shfl_xor(ed0, m, 16);
                ed1 += __shfl_xor(ed1, m, 16);
            }
            if (l16 == 0) esd[orow] = make_float4(es0, es1, ed0, ed1);
        }
    } else if (b < SCT_BLKS + G0_BLKS + WCV_BLKS) {
        // layer-1 W -> bf16 (8192 float4)
        const int i = (b - SCT_BLKS - G0_BLKS) * 256 + t;
        float4 v = ((const float4*)W)[8192 + i];
        ushort4 u; u.x = f2bf(v.x); u.y = f2bf(v.y); u.z = f2bf(v.z); u.w = f2bf(v.w);
        ((ushort4*)wbf)[i] = u;
    } else {
        // x -> out slot0 (fp32) + xbf (bf16), 2 float4/thread
        const float4* x4 = (const float4*)x;
        const int i0 = ((b - SCT_BLKS - G0_BLKS - WCV_BLKS) * 256 + t) * 2;
#pragma unroll
        for (int u = 0; u < 2; u++) {
            const int i = i0 + u;
            float4 v = x4[i];
            out[i] = v;
            ushort4 uu; uu.x = f2bf(v.x); uu.y = f2bf(v.y); uu.z = f2bf(v.z); uu.w = f2bf(v.w);
            xb[i] = uu;
        }
    }
}

// ---------------- layer-1 GEMM (bf16 MFMA, LDS-staged W) + in-wave logits ----------------
__global__ __launch_bounds__(256) void gemm_enode_k(const unsigned short* __restrict__ A,
                                                    const unsigned short* __restrict__ Wb,
                                                    unsigned char* __restrict__ h8,
                                                    const float* __restrict__ a_s,
                                                    const float* __restrict__ a_d,
                                                    float4* __restrict__ esd) {
    __shared__ unsigned short wsd[HC * D_DIM];   // 64 KB
    const int t = threadIdx.x;
    const int wv = t >> 6;
    const int lane = t & 63;
    const int bm = blockIdx.x * 64 + wv * 16;
    const int l16 = lane & 15;
    const int kg = lane >> 4;          // 0..3
#pragma unroll
    for (int i = 0; i < 16; i++) {
        const int idx = i * 256 + t;
        const int r = idx >> 4, c = idx & 15;
        short8v v = *(const short8v*)(Wb + (size_t)idx * 8);
        *(short8v*)(wsd + r * 128 + ((c ^ (r & 15)) * 8)) = v;
    }
    __syncthreads();
    f32x4 acc[16] = {};
#pragma unroll
    for (int kk = 0; kk < 4; kk++) {
        const int k0 = kk * 32 + kg * 8;
        short8v af = *(const short8v*)(A + (size_t)(bm + l16) * 128 + k0);
        const int cc = kk * 4 + kg;
#pragma unroll
        for (int n = 0; n < 16; n++) {
            const int r = n * 16 + l16;
            short8v bf_ = *(const short8v*)(wsd + r * 128 + (((cc ^ l16) & 15) * 8));
            acc[n] = __builtin_amdgcn_mfma_f32_16x16x32_bf16(af, bf_, acc[n], 0, 0, 0);
        }
    }
    float asv[16], adv[16];
#pragma unroll
    for (int n = 0; n < 16; n++) {
        asv[n] = a_s[n * 16 + l16];
        adv[n] = a_d[n * 16 + l16];
    }
#pragma unroll
    for (int r = 0; r < 4; r++) {
        const int orow = bm + kg * 4 + r;
        float es0 = 0.f, es1 = 0.f, ed0 = 0.f, ed1 = 0.f;
        unsigned int pk[4];
#pragma unroll
        for (int nq = 0; nq < 4; nq++)
            pk[nq] = pk4fp8(acc[nq * 4][r], acc[nq * 4 + 1][r],
                            acc[nq * 4 + 2][r], acc[nq * 4 + 3][r]);
#pragma unroll
        for (int n = 0; n < 8; n++)  { es0 += acc[n][r] * asv[n]; ed0 += acc[n][r] * adv[n]; }
#pragma unroll
        for (int n = 8; n < 16; n++) { es1 += acc[n][r] * asv[n]; ed1 += acc[n][r] * adv[n]; }
        *(uint4*)(h8 + (size_t)orow * 256 + l16 * 16) = make_uint4(pk[0], pk[1], pk[2], pk[3]);
#pragma unroll
        for (int m = 1; m < 16; m <<= 1) {
            es0 += __shfl_xor(es0, m, 16);
            es1 += __shfl_xor(es1, m, 16);
            ed0 += __shfl_xor(ed0, m, 16);
            ed1 += __shfl_xor(ed1, m, 16);
        }
        if (l16 == 0) esd[orow] = make_float4(es0, es1, ed0, ed1);
    }
}

// ---------------- per-dst softmax + aggregation (fp8 payload) ----------------
template <int WX>
__global__ __launch_bounds__(256) void agg_k(const unsigned char* __restrict__ h8,
                                             const float4* __restrict__ esd,
                                             const int* __restrict__ deg,
                                             const unsigned short* __restrict__ csrc,
                                             const float* __restrict__ bias, float* __restrict__ out,
                                             unsigned short* __restrict__ xbf) {
    __shared__ unsigned short sS[4][64];
    __shared__ float sP[4][2][64];
    const int lane = threadIdx.x & 63;
    const int wid = threadIdx.x >> 6;
    const int d = blockIdx.x * 4 + wid;
    if (d >= N_NODES) return;
    const int dg = min(deg[d], CAP);
    const int rbase = d * CAP;
    const int q = lane >> 4;           // edge-quarter 0..3
    const int l16 = lane & 15;
    const float4 edv = esd[d];
    float acc[16] = {};
    float sp0 = 0.f, sp1 = 0.f;
    for (int c0 = 0; c0 < dg; c0 += 64) {
        const int cnt = min(64, dg - c0);
        const int padded = (cnt + 15) & ~15;   // multiple of 16 -> whole ILP4 groups
        if (lane < padded) {
            unsigned short s = 0;
            float p0 = 0.f, p1 = 0.f;
            if (lane < cnt) {
                s = csrc[rbase + c0 + lane];
                const float4 e4 = esd[s];
                float e0 = e4.x + edv.z; e0 = e0 > 0.f ? e0 : NEG * e0;
                float e1 = e4.y + edv.w; e1 = e1 > 0.f ? e1 : NEG * e1;
                p0 = __expf(fminf(e0, 60.f));
                p1 = __expf(fminf(e1, 60.f));
                sp0 += p0; sp1 += p1;
            }
            sS[wid][lane] = s;
            sP[wid][0][lane] = p0;
            sP[wid][1][lane] = p1;
        }
        asm volatile("s_waitcnt lgkmcnt(0)" ::: "memory");
        const int iters = padded >> 2;         // edges per quarter, multiple of 4
        for (int i0 = 0; i0 < iters; i0 += 4) {
            float pj0[4], pj1[4];
            uint4 hv[4];
#pragma unroll
            for (int u = 0; u < 4; u++) {
                const int j = 4 * (i0 + u) + q;
                const int sj = sS[wid][j];
                pj0[u] = sP[wid][0][j];
                pj1[u] = sP[wid][1][j];
                hv[u] = *(const uint4*)(h8 + (size_t)sj * 256 + l16 * 16);
            }
#pragma unroll
            for (int u = 0; u < 4; u++) {
                float f[16];
                cvt4fp8(hv[u].x, f);
                cvt4fp8(hv[u].y, f + 4);
                cvt4fp8(hv[u].z, f + 8);
                cvt4fp8(hv[u].w, f + 12);
#pragma unroll
                for (int k = 0; k < 16; k++)
                    acc[k] += (k < 8 ? pj0[u] : pj1[u]) * f[k];
            }
        }
    }
#pragma unroll
    for (int k = 0; k < 16; k++) {
        acc[k] += __shfl_xor(acc[k], 16, 64);
        acc[k] += __shfl_xor(acc[k], 32, 64);
    }
#pragma unroll
    for (int m = 1; m < 64; m <<= 1) {
        sp0 += __shfl_xor(sp0, m, 64);
        sp1 += __shfl_xor(sp1, m, 64);
    }
    const float inv0 = 1.f / sp0;
    const float inv1 = 1.f / sp1;
    float res[8];
#pragma unroll
    for (int k = 0; k < 8; k++)
        res[k] = (acc[k] * inv0 + acc[k + 8] * inv1) * 0.5f;
    if (lane < 16) {
#pragma unroll
        for (int k = 0; k < 8; k++) {
            const int ch = k * 16 + l16;
            float v = res[k] + bias[ch];
            v = v > 0.f ? v : (__expf(v) - 1.f);
            out[(size_t)d * D_DIM + ch] = v;
            if (WX) xbf[(size_t)d * D_DIM + ch] = f2bf(v);
        }
    }
}

extern "C" void kernel_launch(void* const* d_in, const int* in_sizes, int n_in,
                              void* d_out, int out_size, void* d_ws, size_t ws_size,
                              hipStream_t stream) {
    const float* x  = (const float*)d_in[0];
    const int* ei   = (const int*)d_in[1];
    const float* W  = (const float*)d_in[2];
    const float* as_ = (const float*)d_in[3];
    const float* ad_ = (const float*)d_in[4];
    const float* bias = (const float*)d_in[5];
    float* out = (float*)d_out;

    char* ws = (char*)d_ws;
    size_t off = 0;
    auto alloc = [&](size_t bytes) -> void* {
        void* p = ws + off;
        off = (off + bytes + 255) & ~(size_t)255;
        return p;
    };
    unsigned char* h8 = (unsigned char*)alloc((size_t)N_NODES * HC);           // 10.24 MB
    unsigned short* xbf = (unsigned short*)alloc((size_t)N_NODES * D_DIM * 2); // 10.24 MB
    float* esd = (float*)alloc((size_t)N_NODES * 16);                          // 640 KB
    unsigned short* wbf = (unsigned short*)alloc((size_t)HC * D_DIM * 2);      // 64 KB (layer 1)
    int* deg  = (int*)alloc((size_t)N_NODES * 4);
    unsigned short* csrc = (unsigned short*)alloc((size_t)N_NODES * CAP * 2);  // 5.12 MB

    hipMemsetAsync(deg, 0, (size_t)N_NODES * 4, stream);
    // D1: scatter || gemm0+esd0 (32KB LDS) || W1cvt || copy
    fused0_k<<<SCT_BLKS + G0_BLKS + WCV_BLKS + CPY_BLKS, 256, 0, stream>>>(
        ei, deg, csrc, x, W, h8, as_, ad_, (float4*)esd, wbf, (float4*)out, (ushort4*)xbf);

    const size_t nd = (size_t)N_NODES * D_DIM;
    const int AGG_BLKS = (N_NODES + 3) / 4;
    // D2: agg layer 0
    agg_k<1><<<AGG_BLKS, 256, 0, stream>>>(h8, (const float4*)esd, deg, csrc,
                                           bias, out + nd, xbf);
    // D3: gemm layer 1 (+esd for layer 1)
    gemm_enode_k<<<625, 256, 0, stream>>>(xbf, wbf, h8, as_ + HC, ad_ + HC, (float4*)esd);
    // D4: agg layer 1
    agg_k<0><<<AGG_BLKS, 256, 0, stream>>>(h8, (const float4*)esd, deg, csrc,
                                           bias + D_DIM, out + 2 * nd, xbf);
}

// Round 19
// 135.488 us; speedup vs baseline: 1.1909x; 1.1909x over previous
//
#include <hip/hip_runtime.h>
#include <hip/hip_bf16.h>
#include <hip/hip_fp8.h>

#define N_NODES 40000
#define N_EDGES 640000
#define ETOT    (N_NODES + N_EDGES)   // 680000
#define D_DIM   128
#define HC      256                   // H*C
#define NEG     0.2f
#define CAP     64                    // fixed CSR row stride (max deg well under 64)

typedef short short8v __attribute__((ext_vector_type(8)));
typedef float f32x4 __attribute__((ext_vector_type(4)));
typedef float f32x2 __attribute__((ext_vector_type(2)));

static __device__ __forceinline__ float bf2f(unsigned short u) {
    return __uint_as_float(((unsigned)u) << 16);
}
static __device__ __forceinline__ unsigned short f2bf(float f) {
    __hip_bfloat16 b = __float2bfloat16(f);
    unsigned short r;
    __builtin_memcpy(&r, &b, 2);
    return r;
}
static __device__ __forceinline__ unsigned char f2fp8(float f) {
    __hip_fp8_e4m3 v(f);
    return (unsigned char)v.__x;
}
static __device__ __forceinline__ unsigned int pk4fp8(float a, float b, float c, float d) {
#if __has_builtin(__builtin_amdgcn_cvt_pk_fp8_f32)
    int w = __builtin_amdgcn_cvt_pk_fp8_f32(a, b, 0, false);
    w = __builtin_amdgcn_cvt_pk_fp8_f32(c, d, w, true);
    return (unsigned int)w;
#else
    return (unsigned int)f2fp8(a) | ((unsigned int)f2fp8(b) << 8) |
           ((unsigned int)f2fp8(c) << 16) | ((unsigned int)f2fp8(d) << 24);
#endif
}
static __device__ __forceinline__ void cvt4fp8(unsigned int w, float* f) {
#if __has_builtin(__builtin_amdgcn_cvt_pk_f32_fp8)
    f32x2 lo = __builtin_amdgcn_cvt_pk_f32_fp8(w, false);
    f32x2 hi = __builtin_amdgcn_cvt_pk_f32_fp8(w, true);
    f[0] = lo[0]; f[1] = lo[1]; f[2] = hi[0]; f[3] = hi[1];
#else
    for (int i = 0; i < 4; i++) {
        __hip_fp8_e4m3 v; v.__x = (unsigned char)(w >> (8 * i));
        f[i] = (float)v;
    }
#endif
}

// ---------------- fused D1: interleaved scatter/gemm0 || W1cvt || copy ----------------
// Blocks 0..1249: even -> scatter block b/2, odd -> gemm block b/2 (co-resident per CU).
// Then scatter tail 625..664, W1 cvt, x copy.
#define SCT_BLKS 665           // 665*1024 >= 680000, 4 edges/thread
#define G0_BLKS  625
#define WCV_BLKS 32            // 8192 float4 of layer-1 W
#define CPY_BLKS 2500          // 1280000 float4, 2 per thread
#define IL_BLKS  (2 * G0_BLKS)                 // 1250
#define TAIL0    (IL_BLKS + (SCT_BLKS - G0_BLKS))   // 1290
#define TAIL1    (TAIL0 + WCV_BLKS)                 // 1322
__global__ __launch_bounds__(256) void fused0_k(const int* __restrict__ ei, int* __restrict__ deg,
                                                unsigned short* __restrict__ csrc,
                                                const float* __restrict__ x,
                                                const float* __restrict__ W,
                                                unsigned char* __restrict__ h8,
                                                const float* __restrict__ a_s,
                                                const float* __restrict__ a_d,
                                                float4* __restrict__ esd,
                                                unsigned short* __restrict__ wbf,
                                                float4* __restrict__ out,
                                                ushort4* __restrict__ xb) {
    __shared__ unsigned short wsd[HC * D_DIM];   // 64 KB
    const int b = blockIdx.x;
    const int t = threadIdx.x;
    int role, idx;
    if (b < IL_BLKS)      { role = (b & 1);            idx = b >> 1; }            // 0=scatter,1=gemm
    else if (b < TAIL0)   { role = 0;                  idx = G0_BLKS + (b - IL_BLKS); }
    else if (b < TAIL1)   { role = 2;                  idx = b - TAIL0; }
    else                  { role = 3;                  idx = b - TAIL1; }

    if (role == 0) {
        const int e0 = idx * 1024 + t;
#pragma unroll
        for (int u = 0; u < 4; u++) {
            const int e = e0 + u * 256;
            if (e < ETOT) {
                int ss, dd;
                if (e < N_EDGES) { ss = ei[e]; dd = ei[N_EDGES + e]; }
                else             { ss = e - N_EDGES; dd = ss; }
                int pos = atomicAdd(&deg[dd], 1);
                if (pos < CAP) csrc[dd * CAP + pos] = (unsigned short)ss;
            }
        }
    } else if (role == 1) {
        const int wv = t >> 6;
        const int lane = t & 63;
        const int bm = idx * 64 + wv * 16;
        const int l16 = lane & 15;
        const int kg = lane >> 4;      // 0..3
        // stage layer-0 W (fp32) into LDS as bf16, swizzled
#pragma unroll
        for (int i = 0; i < 16; i++) {
            const int iw = i * 256 + t;
            const int r = iw >> 4, c = iw & 15;
            const float* wp = W + (size_t)iw * 8;
            float4 w0 = *(const float4*)wp;
            float4 w1 = *(const float4*)(wp + 4);
            short8v v;
            v[0] = (short)f2bf(w0.x); v[1] = (short)f2bf(w0.y);
            v[2] = (short)f2bf(w0.z); v[3] = (short)f2bf(w0.w);
            v[4] = (short)f2bf(w1.x); v[5] = (short)f2bf(w1.y);
            v[6] = (short)f2bf(w1.z); v[7] = (short)f2bf(w1.w);
            *(short8v*)(wsd + r * 128 + ((c ^ (r & 15)) * 8)) = v;
        }
        __syncthreads();
        f32x4 acc[16] = {};
#pragma unroll
        for (int kk = 0; kk < 4; kk++) {
            const int k0 = kk * 32 + kg * 8;
            const float* ap = x + (size_t)(bm + l16) * 128 + k0;
            float4 a0 = *(const float4*)ap;
            float4 a1 = *(const float4*)(ap + 4);
            short8v af;
            af[0] = (short)f2bf(a0.x); af[1] = (short)f2bf(a0.y);
            af[2] = (short)f2bf(a0.z); af[3] = (short)f2bf(a0.w);
            af[4] = (short)f2bf(a1.x); af[5] = (short)f2bf(a1.y);
            af[6] = (short)f2bf(a1.z); af[7] = (short)f2bf(a1.w);
            const int cc = kk * 4 + kg;
#pragma unroll
            for (int n = 0; n < 16; n++) {
                const int r = n * 16 + l16;
                short8v bf_ = *(const short8v*)(wsd + r * 128 + (((cc ^ l16) & 15) * 8));
                acc[n] = __builtin_amdgcn_mfma_f32_16x16x32_bf16(af, bf_, acc[n], 0, 0, 0);
            }
        }
        float asv[16], adv[16];
#pragma unroll
        for (int n = 0; n < 16; n++) {
            asv[n] = a_s[n * 16 + l16];
            adv[n] = a_d[n * 16 + l16];
        }
#pragma unroll
        for (int r = 0; r < 4; r++) {
            const int orow = bm + kg * 4 + r;
            float es0 = 0.f, es1 = 0.f, ed0 = 0.f, ed1 = 0.f;
            unsigned int pk[4];
#pragma unroll
            for (int nq = 0; nq < 4; nq++)
                pk[nq] = pk4fp8(acc[nq * 4][r], acc[nq * 4 + 1][r],
                                acc[nq * 4 + 2][r], acc[nq * 4 + 3][r]);
#pragma unroll
            for (int n = 0; n < 8; n++)  { es0 += acc[n][r] * asv[n]; ed0 += acc[n][r] * adv[n]; }
#pragma unroll
            for (int n = 8; n < 16; n++) { es1 += acc[n][r] * asv[n]; ed1 += acc[n][r] * adv[n]; }
            *(uint4*)(h8 + (size_t)orow * 256 + l16 * 16) = make_uint4(pk[0], pk[1], pk[2], pk[3]);
#pragma unroll
            for (int m = 1; m < 16; m <<= 1) {
                es0 += __shfl_xor(es0, m, 16);
                es1 += __shfl_xor(es1, m, 16);
                ed0 += __shfl_xor(ed0, m, 16);
                ed1 += __shfl_xor(ed1, m, 16);
            }
            if (l16 == 0) esd[orow] = make_float4(es0, es1, ed0, ed1);
        }
    } else if (role == 2) {
        // layer-1 W -> bf16 (8192 float4)
        const int i = idx * 256 + t;
        float4 v = ((const float4*)W)[8192 + i];
        ushort4 u; u.x = f2bf(v.x); u.y = f2bf(v.y); u.z = f2bf(v.z); u.w = f2bf(v.w);
        ((ushort4*)wbf)[i] = u;
    } else {
        // x -> out slot0 (fp32) + xbf (bf16), 2 float4/thread
        const float4* x4 = (const float4*)x;
        const int i0 = (idx * 256 + t) * 2;
#pragma unroll
        for (int u = 0; u < 2; u++) {
            const int i = i0 + u;
            float4 v = x4[i];
            out[i] = v;
            ushort4 uu; uu.x = f2bf(v.x); uu.y = f2bf(v.y); uu.z = f2bf(v.z); uu.w = f2bf(v.w);
            xb[i] = uu;
        }
    }
}

// ---------------- layer-1 GEMM (bf16 MFMA, LDS-staged W) + in-wave logits ----------------
__global__ __launch_bounds__(256) void gemm_enode_k(const unsigned short* __restrict__ A,
                                                    const unsigned short* __restrict__ Wb,
                                                    unsigned char* __restrict__ h8,
                                                    const float* __restrict__ a_s,
                                                    const float* __restrict__ a_d,
                                                    float4* __restrict__ esd) {
    __shared__ unsigned short wsd[HC * D_DIM];   // 64 KB
    const int t = threadIdx.x;
    const int wv = t >> 6;
    const int lane = t & 63;
    const int bm = blockIdx.x * 64 + wv * 16;
    const int l16 = lane & 15;
    const int kg = lane >> 4;          // 0..3
#pragma unroll
    for (int i = 0; i < 16; i++) {
        const int idx = i * 256 + t;
        const int r = idx >> 4, c = idx & 15;
        short8v v = *(const short8v*)(Wb + (size_t)idx * 8);
        *(short8v*)(wsd + r * 128 + ((c ^ (r & 15)) * 8)) = v;
    }
    __syncthreads();
    f32x4 acc[16] = {};
#pragma unroll
    for (int kk = 0; kk < 4; kk++) {
        const int k0 = kk * 32 + kg * 8;
        short8v af = *(const short8v*)(A + (size_t)(bm + l16) * 128 + k0);
        const int cc = kk * 4 + kg;
#pragma unroll
        for (int n = 0; n < 16; n++) {
            const int r = n * 16 + l16;
            short8v bf_ = *(const short8v*)(wsd + r * 128 + (((cc ^ l16) & 15) * 8));
            acc[n] = __builtin_amdgcn_mfma_f32_16x16x32_bf16(af, bf_, acc[n], 0, 0, 0);
        }
    }
    float asv[16], adv[16];
#pragma unroll
    for (int n = 0; n < 16; n++) {
        asv[n] = a_s[n * 16 + l16];
        adv[n] = a_d[n * 16 + l16];
    }
#pragma unroll
    for (int r = 0; r < 4; r++) {
        const int orow = bm + kg * 4 + r;
        float es0 = 0.f, es1 = 0.f, ed0 = 0.f, ed1 = 0.f;
        unsigned int pk[4];
#pragma unroll
        for (int nq = 0; nq < 4; nq++)
            pk[nq] = pk4fp8(acc[nq * 4][r], acc[nq * 4 + 1][r],
                            acc[nq * 4 + 2][r], acc[nq * 4 + 3][r]);
#pragma unroll
        for (int n = 0; n < 8; n++)  { es0 += acc[n][r] * asv[n]; ed0 += acc[n][r] * adv[n]; }
#pragma unroll
        for (int n = 8; n < 16; n++) { es1 += acc[n][r] * asv[n]; ed1 += acc[n][r] * adv[n]; }
        *(uint4*)(h8 + (size_t)orow * 256 + l16 * 16) = make_uint4(pk[0], pk[1], pk[2], pk[3]);
#pragma unroll
        for (int m = 1; m < 16; m <<= 1) {
            es0 += __shfl_xor(es0, m, 16);
            es1 += __shfl_xor(es1, m, 16);
            ed0 += __shfl_xor(ed0, m, 16);
            ed1 += __shfl_xor(ed1, m, 16);
        }
        if (l16 == 0) esd[orow] = make_float4(es0, es1, ed0, ed1);
    }
}

// ---------------- per-dst softmax + aggregation (fp8 payload) ----------------
template <int WX>
__global__ __launch_bounds__(256) void agg_k(const unsigned char* __restrict__ h8,
                                             const float4* __restrict__ esd,
                                             const int* __restrict__ deg,
                                             const unsigned short* __restrict__ csrc,
                                             const float* __restrict__ bias, float* __restrict__ out,
                                             unsigned short* __restrict__ xbf) {
    __shared__ unsigned short sS[4][64];
    __shared__ float sP[4][2][64];
    const int lane = threadIdx.x & 63;
    const int wid = threadIdx.x >> 6;
    const int d = blockIdx.x * 4 + wid;
    if (d >= N_NODES) return;
    const int dg = min(deg[d], CAP);
    const int rbase = d * CAP;
    const int q = lane >> 4;           // edge-quarter 0..3
    const int l16 = lane & 15;
    const float4 edv = esd[d];
    float acc[16] = {};
    float sp0 = 0.f, sp1 = 0.f;
    for (int c0 = 0; c0 < dg; c0 += 64) {
        const int cnt = min(64, dg - c0);
        const int padded = (cnt + 15) & ~15;   // multiple of 16 -> whole ILP4 groups
        if (lane < padded) {
            unsigned short s = 0;
            float p0 = 0.f, p1 = 0.f;
            if (lane < cnt) {
                s = csrc[rbase + c0 + lane];
                const float4 e4 = esd[s];
                float e0 = e4.x + edv.z; e0 = e0 > 0.f ? e0 : NEG * e0;
                float e1 = e4.y + edv.w; e1 = e1 > 0.f ? e1 : NEG * e1;
                p0 = __expf(fminf(e0, 60.f));
                p1 = __expf(fminf(e1, 60.f));
                sp0 += p0; sp1 += p1;
            }
            sS[wid][lane] = s;
            sP[wid][0][lane] = p0;
            sP[wid][1][lane] = p1;
        }
        asm volatile("s_waitcnt lgkmcnt(0)" ::: "memory");
        const int iters = padded >> 2;         // edges per quarter, multiple of 4
        for (int i0 = 0; i0 < iters; i0 += 4) {
            float pj0[4], pj1[4];
            uint4 hv[4];
#pragma unroll
            for (int u = 0; u < 4; u++) {
                const int j = 4 * (i0 + u) + q;
                const int sj = sS[wid][j];
                pj0[u] = sP[wid][0][j];
                pj1[u] = sP[wid][1][j];
                hv[u] = *(const uint4*)(h8 + (size_t)sj * 256 + l16 * 16);
            }
#pragma unroll
            for (int u = 0; u < 4; u++) {
                float f[16];
                cvt4fp8(hv[u].x, f);
                cvt4fp8(hv[u].y, f + 4);
                cvt4fp8(hv[u].z, f + 8);
                cvt4fp8(hv[u].w, f + 12);
#pragma unroll
                for (int k = 0; k < 16; k++)
                    acc[k] += (k < 8 ? pj0[u] : pj1[u]) * f[k];
            }
        }
    }
#pragma unroll
    for (int k = 0; k < 16; k++) {
        acc[k] += __shfl_xor(acc[k], 16, 64);
        acc[k] += __shfl_xor(acc[k], 32, 64);
    }
#pragma unroll
    for (int m = 1; m < 64; m <<= 1) {
        sp0 += __shfl_xor(sp0, m, 64);
        sp1 += __shfl_xor(sp1, m, 64);
    }
    const float inv0 = 1.f / sp0;
    const float inv1 = 1.f / sp1;
    float res[8];
#pragma unroll
    for (int k = 0; k < 8; k++)
        res[k] = (acc[k] * inv0 + acc[k + 8] * inv1) * 0.5f;
    if (lane < 16) {
#pragma unroll
        for (int k = 0; k < 8; k++) {
            const int ch = k * 16 + l16;
            float v = res[k] + bias[ch];
            v = v > 0.f ? v : (__expf(v) - 1.f);
            out[(size_t)d * D_DIM + ch] = v;
            if (WX) xbf[(size_t)d * D_DIM + ch] = f2bf(v);
        }
    }
}

extern "C" void kernel_launch(void* const* d_in, const int* in_sizes, int n_in,
                              void* d_out, int out_size, void* d_ws, size_t ws_size,
                              hipStream_t stream) {
    const float* x  = (const float*)d_in[0];
    const int* ei   = (const int*)d_in[1];
    const float* W  = (const float*)d_in[2];
    const float* as_ = (const float*)d_in[3];
    const float* ad_ = (const float*)d_in[4];
    const float* bias = (const float*)d_in[5];
    float* out = (float*)d_out;

    char* ws = (char*)d_ws;
    size_t off = 0;
    auto alloc = [&](size_t bytes) -> void* {
        void* p = ws + off;
        off = (off + bytes + 255) & ~(size_t)255;
        return p;
    };
    unsigned char* h8 = (unsigned char*)alloc((size_t)N_NODES * HC);           // 10.24 MB
    unsigned short* xbf = (unsigned short*)alloc((size_t)N_NODES * D_DIM * 2); // 10.24 MB
    float* esd = (float*)alloc((size_t)N_NODES * 16);                          // 640 KB
    unsigned short* wbf = (unsigned short*)alloc((size_t)HC * D_DIM * 2);      // 64 KB (layer 1)
    int* deg  = (int*)alloc((size_t)N_NODES * 4);
    unsigned short* csrc = (unsigned short*)alloc((size_t)N_NODES * CAP * 2);  // 5.12 MB

    hipMemsetAsync(deg, 0, (size_t)N_NODES * 4, stream);
    // D1: interleaved scatter/gemm0 || W1cvt || copy
    fused0_k<<<TAIL1 + CPY_BLKS, 256, 0, stream>>>(
        ei, deg, csrc, x, W, h8, as_, ad_, (float4*)esd, wbf, (float4*)out, (ushort4*)xbf);

    const size_t nd = (size_t)N_NODES * D_DIM;
    const int AGG_BLKS = (N_NODES + 3) / 4;
    // D2: agg layer 0
    agg_k<1><<<AGG_BLKS, 256, 0, stream>>>(h8, (const float4*)esd, deg, csrc,
                                           bias, out + nd, xbf);
    // D3: gemm layer 1 (+esd for layer 1)
    gemm_enode_k<<<625, 256, 0, stream>>>(xbf, wbf, h8, as_ + HC, ad_ + HC, (float4*)esd);
    // D4: agg layer 1
    agg_k<0><<<AGG_BLKS, 256, 0, stream>>>(h8, (const float4*)esd, deg, csrc,
                                           bias + D_DIM, out + 2 * nd, xbf);
}